// Round 1
// baseline (2175.406 us; speedup 1.0000x reference)
//
#include <hip/hip_runtime.h>

#define T_STEPS 20
#define NB      64
#define CIN     12
#define LLEN    4096
#define C1N     64
#define C2N     64
#define TL      128
#define NTHR    256

// ws layout (in floats)
#define WT1_OFF  0                         // [CIN*3][C1N] = 2304
#define WT2_OFF  (CIN*3*C1N)               // [C1N*3][C2N] = 12288
#define POOL_OFF (WT2_OFF + C1N*3*C2N)     // [NB][C2N] = 4096

// ---------------------------------------------------------------------------
// Transpose weights to [ci][k][cout] so per-(ci,k) weight rows are contiguous
// and wave-uniform reads become s_load_dwordx16 (scalar pipe, free for VALU).
// ---------------------------------------------------------------------------
__global__ __launch_bounds__(NTHR) void prep_weights(
    const float* __restrict__ w1, const float* __restrict__ w2,
    float* __restrict__ ws)
{
    int i = blockIdx.x * NTHR + threadIdx.x;
    if (i < C1N * CIN * 3) {
        int c1 = i / (CIN * 3), r = i % (CIN * 3);     // r = ci*3 + k
        ws[WT1_OFF + r * C1N + c1] = w1[i];
    }
    if (i < C2N * C1N * 3) {
        int c2 = i / (C1N * 3), r = i % (C1N * 3);
        ws[WT2_OFF + r * C2N + c2] = w2[i];
    }
}

// ---------------------------------------------------------------------------
// Main SNN kernel. Block = (b, l-tile of 128). Wave w owns channels
// [16w, 16w+16) for both conv1 outputs and conv2 outputs; lanes map to l.
// Layer-1 is stateless (TAU1=1 => v1 == i1), so s1 (incl. halo) is recomputed
// per tile from x each timestep. v2/acc persist in registers across t.
// ---------------------------------------------------------------------------
__global__ __launch_bounds__(NTHR) void snn_main(
    const float* __restrict__ xg,
    const float* __restrict__ b1g,
    const float* __restrict__ b2g,
    const float* __restrict__ gp,
    const float* __restrict__ t1p,
    const float* __restrict__ t2p,
    const float* __restrict__ ws,
    float* __restrict__ pooled)
{
    __shared__ float         xs[CIN][TL + 4];      // x tile, block coords [-2, TL+2)
    __shared__ unsigned char s1s[C1N][TL + 2];     // spikes, block coords [-1, TL+1)

    const int tid  = threadIdx.x;
    const int lane = tid & 63;
    const int wv   = __builtin_amdgcn_readfirstlane(tid >> 6);  // wave id, uniform
    const int cb   = wv * 16;                                   // channel base
    const int b    = blockIdx.y;
    const int l0   = blockIdx.x * TL;

    const float gain = gp[0], th1 = t1p[0], th2 = t2p[0];
    const float* __restrict__ wT1 = ws + WT1_OFF;
    const float* __restrict__ wT2 = ws + WT2_OFF;

    float v2[2][16], acc[2][16];
#pragma unroll
    for (int lc = 0; lc < 2; ++lc)
#pragma unroll
        for (int j = 0; j < 16; ++j) { v2[lc][j] = 0.f; acc[lc][j] = 0.f; }

    float b1v[16], b2v[16];
#pragma unroll
    for (int j = 0; j < 16; ++j) { b1v[j] = b1g[cb + j]; b2v[j] = b2g[cb + j]; }

    const long xbase = (long)b * CIN * LLEN * T_STEPS;

#pragma unroll 1
    for (int t = 0; t < T_STEPS; ++t) {
        // ---- stage x[b, :, l0-2 .. l0+TL+2, t] (zero-padded) ----
#pragma unroll 1
        for (int i = tid; i < CIN * (TL + 4); i += NTHR) {
            int ci = i / (TL + 4);
            int p  = i - ci * (TL + 4);
            int gl = l0 - 2 + p;
            float v = 0.f;
            if ((unsigned)gl < (unsigned)LLEN)
                v = xg[xbase + ((long)ci * LLEN + gl) * T_STEPS + t];
            xs[ci][p] = v;
        }
        __syncthreads();

        // ---- conv1 -> spikes; s1 col sl covers block l in [-1, TL+1) ----
#pragma unroll 1
        for (int lp = 0; lp < 3; ++lp) {
            int sl = lp * 64 + lane;
            if (sl < TL + 2) {
                float a1[16];
#pragma unroll
                for (int j = 0; j < 16; ++j) a1[j] = b1v[j];
#pragma unroll 4
                for (int ci = 0; ci < CIN; ++ci) {
                    float x0 = xs[ci][sl + 0];
                    float x1 = xs[ci][sl + 1];
                    float x2 = xs[ci][sl + 2];
                    const float* w0 = wT1 + (ci * 3 + 0) * C1N + cb;
                    const float* w1 = wT1 + (ci * 3 + 1) * C1N + cb;
                    const float* w2 = wT1 + (ci * 3 + 2) * C1N + cb;
#pragma unroll
                    for (int j = 0; j < 16; ++j) {
                        a1[j] = fmaf(w0[j], x0, a1[j]);
                        a1[j] = fmaf(w1[j], x1, a1[j]);
                        a1[j] = fmaf(w2[j], x2, a1[j]);
                    }
                }
                int  gls   = l0 - 1 + sl;
                bool valid = (unsigned)gls < (unsigned)LLEN;   // global zero-pad
#pragma unroll
                for (int j = 0; j < 16; ++j) {
                    unsigned char sp = (valid && (a1[j] * gain >= th1)) ? 1 : 0;
                    s1s[cb + j][sl] = sp;
                }
            }
        }
        __syncthreads();

        // ---- conv2 over s1 + LIF update (state in registers) ----
#pragma unroll
        for (int lc = 0; lc < 2; ++lc) {
            int l = lc * 64 + lane;          // output l in [0, TL)
            float a2[16];
#pragma unroll
            for (int j = 0; j < 16; ++j) a2[j] = 0.f;
#pragma unroll 4
            for (int ci = 0; ci < C1N; ++ci) {
                float s0 = (float)s1s[ci][l + 0];
                float s1 = (float)s1s[ci][l + 1];
                float s2 = (float)s1s[ci][l + 2];
                const float* w0 = wT2 + (ci * 3 + 0) * C2N + cb;
                const float* w1 = wT2 + (ci * 3 + 1) * C2N + cb;
                const float* w2 = wT2 + (ci * 3 + 2) * C2N + cb;
#pragma unroll
                for (int j = 0; j < 16; ++j) {
                    a2[j] = fmaf(w0[j], s0, a2[j]);
                    a2[j] = fmaf(w1[j], s1, a2[j]);
                    a2[j] = fmaf(w2[j], s2, a2[j]);
                }
            }
#pragma unroll
            for (int j = 0; j < 16; ++j) {
                float i2 = (a2[j] + b2v[j]) * gain;
                float v  = v2[lc][j] + (i2 - v2[lc][j]) * (1.0f / 0.9f);
                float sp = (v >= th2) ? 1.f : 0.f;
                v2[lc][j]  = (v >= th2) ? 0.f : v;
                acc[lc][j] += sp;
            }
        }
        __syncthreads();
    }

    // ---- reduce acc over l (within wave) -> pooled[b][c2] ----
#pragma unroll
    for (int j = 0; j < 16; ++j) {
        float s = acc[0][j] + acc[1][j];
#pragma unroll
        for (int off = 32; off > 0; off >>= 1)
            s += __shfl_down(s, off, 64);
        if (lane == 0) atomicAdd(&pooled[b * C2N + cb + j], s);
    }
}

// ---------------------------------------------------------------------------
// logits[b][cls] = fc_b[cls] + sum_c pooled[b][c]/(T*L) * fc_w[cls][c]
// ---------------------------------------------------------------------------
__global__ __launch_bounds__(NTHR) void fc_kernel(
    const float* __restrict__ pooled,
    const float* __restrict__ fcw,
    const float* __restrict__ fcb,
    float* __restrict__ out)
{
    int i   = threadIdx.x;          // 256 = 64 b * 4 cls
    int b   = i >> 2;
    int cls = i & 3;
    float s = 0.f;
#pragma unroll 8
    for (int c = 0; c < C2N; ++c)
        s += pooled[b * C2N + c] * fcw[cls * C2N + c];
    out[b * 4 + cls] = s * (1.0f / ((float)T_STEPS * (float)LLEN)) + fcb[cls];
}

extern "C" void kernel_launch(void* const* d_in, const int* in_sizes, int n_in,
                              void* d_out, int out_size, void* d_ws, size_t ws_size,
                              hipStream_t stream)
{
    const float* xg  = (const float*)d_in[0];
    const float* w1  = (const float*)d_in[1];
    const float* b1  = (const float*)d_in[2];
    const float* w2  = (const float*)d_in[3];
    const float* b2  = (const float*)d_in[4];
    const float* gp  = (const float*)d_in[5];
    const float* t1  = (const float*)d_in[6];
    const float* t2  = (const float*)d_in[7];
    const float* fcw = (const float*)d_in[8];
    const float* fcb = (const float*)d_in[9];
    float* ws  = (float*)d_ws;
    float* out = (float*)d_out;

    hipMemsetAsync(ws + POOL_OFF, 0, NB * C2N * sizeof(float), stream);
    prep_weights<<<(C2N * C1N * 3 + NTHR - 1) / NTHR, NTHR, 0, stream>>>(w1, w2, ws);
    snn_main<<<dim3(LLEN / TL, NB), NTHR, 0, stream>>>(xg, b1, b2, gp, t1, t2,
                                                       ws, ws + POOL_OFF);
    fc_kernel<<<1, NTHR, 0, stream>>>(ws + POOL_OFF, fcw, fcb, out);
}

// Round 2
// 1878.007 us; speedup vs baseline: 1.1584x; 1.1584x over previous
//
#include <hip/hip_runtime.h>

#define T_STEPS 20
#define NB      64
#define CIN     12
#define LLEN    4096
#define C1N     64
#define C2N     64
#define TL      128
#define NTHR    256
#define S1ROWS  (TL + 2)      // 130 spike rows: block l in [-1, TL+1)
#define S1PITCH 72            // ushorts per row: 64 + 8 pad (bank spread, 16B-mult)
#define TXL     256           // transpose l-chunk

// ---- ws layout ----
#define W1T_OFF_F   0                     // float [36][64]
#define POOL_OFF_F  2304                  // float [64][64]
#define W2BF_OFF_B  25600                 // ushort [2 hilo][3 dk][c2 64][ci 64]
#define XT_OFF_B    (1u << 20)            // float [b][ci][t][l]
#define XT_BYTES    ((size_t)NB * CIN * T_STEPS * LLEN * 4)
#define WS_NEED_B   ((size_t)XT_OFF_B + XT_BYTES)

using bf16x8 = __attribute__((ext_vector_type(8))) short;
using f32x4  = __attribute__((ext_vector_type(4))) float;

__device__ inline unsigned short f32_to_bf16_rne(float f) {
    unsigned u = __builtin_bit_cast(unsigned, f);
    return (unsigned short)((u + 0x7FFFu + ((u >> 16) & 1u)) >> 16);
}

// ---------------------------------------------------------------------------
// Weight prep: w1 -> [ci*3+k][c1] fp32 (wave-uniform scalar loads in conv1);
// w2 -> bf16 hi/lo split, layout [hilo][dk][c2][ci] (ci contiguous so a lane's
// 8 B-fragment elements are one 16B load). hi+lo represents w2 to ~2^-18 rel.
// ---------------------------------------------------------------------------
__global__ __launch_bounds__(NTHR) void prep_weights(
    const float* __restrict__ w1, const float* __restrict__ w2,
    float* __restrict__ ws)
{
    int i = blockIdx.x * NTHR + threadIdx.x;
    float* w1t = ws + W1T_OFF_F;
    unsigned short* w2b = (unsigned short*)((char*)ws + W2BF_OFF_B);
    if (i < C1N * CIN * 3) {
        int c1 = i / (CIN * 3), r = i % (CIN * 3);
        w1t[r * C1N + c1] = w1[i];
    }
    if (i < C2N * C1N * 3) {
        int dk = i % 3, rem = i / 3;
        int ci = rem % C1N, c2 = rem / C1N;
        float w = w2[i];
        unsigned short hi = f32_to_bf16_rne(w);
        float hif = __builtin_bit_cast(float, (unsigned)hi << 16);
        unsigned short lo = f32_to_bf16_rne(w - hif);
        w2b[((0 * 3 + dk) * C2N + c2) * C1N + ci] = hi;
        w2b[((1 * 3 + dk) * C2N + c2) * C1N + ci] = lo;
    }
}

// ---------------------------------------------------------------------------
// x [b][ci][l][t] -> xT [b][ci][t][l]: coalesced reads (lane-consecutive
// dwords), LDS pitch 21 (coprime w/ 32 banks), coalesced writes. One HBM
// read + one write of x total (504 MB), so snn_main staging fetches each
// byte exactly once afterwards.
// ---------------------------------------------------------------------------
__global__ __launch_bounds__(NTHR) void transpose_x(
    const float* __restrict__ xg, float* __restrict__ xt)
{
    __shared__ float tile[TXL * 21];
    const int tid = threadIdx.x;
    const int l0  = blockIdx.x * TXL;
    const int bci = blockIdx.y;                 // b*CIN + ci
    const float* src = xg + ((size_t)bci * LLEN + l0) * T_STEPS;
#pragma unroll
    for (int k = 0; k < TXL * T_STEPS / NTHR; ++k) {   // 20 coalesced reads
        int e = tid + k * NTHR;
        tile[(e / T_STEPS) * 21 + (e % T_STEPS)] = src[e];
    }
    __syncthreads();
    float* dst = xt + (size_t)bci * T_STEPS * LLEN + l0;
#pragma unroll
    for (int t = 0; t < T_STEPS; ++t)
        dst[(size_t)t * LLEN + tid] = tile[tid * 21 + t];
}

// ---------------------------------------------------------------------------
// Main kernel. Block = (b, 128-l tile); 4 waves. conv1 stays fp32 VALU
// (s1 bit-exact); conv2 runs on the MFMA pipe (bf16 hi/lo, fp32 acc) and
// co-issues with conv1 VALU across resident waves (m114). Wave w owns
// c1-channels 16w..16w+15 for conv1 AND c2-tile 16w..16w+15 for conv2.
// ---------------------------------------------------------------------------
__global__ __launch_bounds__(NTHR) void snn_main(
    const float* __restrict__ xg, const float* __restrict__ xt, int use_xt,
    const float* __restrict__ b1g, const float* __restrict__ b2g,
    const float* __restrict__ gp, const float* __restrict__ t1p,
    const float* __restrict__ t2p,
    const float* __restrict__ ws, float* __restrict__ pooled)
{
    __shared__ __align__(16) float          xs[CIN][TL + 4];      // x, block l in [-2, TL+2)
    __shared__ __align__(16) unsigned short s1t[S1ROWS][S1PITCH]; // spikes as bf16 bits, [l+1][ci]

    const int tid  = threadIdx.x;
    const int lane = tid & 63;
    const int wv   = __builtin_amdgcn_readfirstlane(tid >> 6);
    const int cb   = wv * 16;
    const int b    = blockIdx.y;
    const int l0   = blockIdx.x * TL;

    const float gain = gp[0], th1 = t1p[0], th2 = t2p[0];
    const float* __restrict__ wT1 = ws + W1T_OFF_F;
    const unsigned short* __restrict__ w2b =
        (const unsigned short*)((const char*)ws + W2BF_OFF_B);

    // --- B fragments (weights) held in registers for the whole kernel ---
    // B[k=ci][n=c2]: lane holds B[(lane>>4)*8+j][lane&15], i.e. 8 contiguous
    // ci for its c2 -> one 16B load from the [hilo][dk][c2][ci] layout.
    bf16x8 bw[2][3][2];
    {
        int c2  = cb + (lane & 15);
        int ci0 = ((lane >> 4) & 3) * 8;
#pragma unroll
        for (int h = 0; h < 2; ++h)
#pragma unroll
            for (int dk = 0; dk < 3; ++dk)
#pragma unroll
                for (int cc = 0; cc < 2; ++cc)
                    bw[h][dk][cc] = *(const bf16x8*)
                        (w2b + (((h * 3 + dk) * C2N + c2) * C1N + cc * 32 + ci0));
    }
    const float b2v = b2g[cb + (lane & 15)];

    float b1v[16];
#pragma unroll
    for (int j = 0; j < 16; ++j) b1v[j] = b1g[cb + j];

    // LIF state, C/D layout: lane holds (l = lt*16 + (lane>>4)*4 + r, c2 = cb + (lane&15))
    float v2s[8][4], accs[8][4];
#pragma unroll
    for (int lt = 0; lt < 8; ++lt)
#pragma unroll
        for (int r = 0; r < 4; ++r) { v2s[lt][r] = 0.f; accs[lt][r] = 0.f; }

    const size_t xbase = (size_t)b * CIN * LLEN * T_STEPS;

#pragma unroll 1
    for (int t = 0; t < T_STEPS; ++t) {
        // ---- stage x[b, :, l0-2 .. l0+TL+2, t] ----
        if (use_xt) {
#pragma unroll 1
            for (int i = tid; i < CIN * (TL + 4); i += NTHR) {
                int ci = i / (TL + 4), p = i - ci * (TL + 4);
                int gl = l0 - 2 + p;
                float v = 0.f;
                if ((unsigned)gl < (unsigned)LLEN)
                    v = xt[((size_t)(b * CIN + ci) * T_STEPS + t) * LLEN + gl];
                xs[ci][p] = v;
            }
        } else {
#pragma unroll 1
            for (int i = tid; i < CIN * (TL + 4); i += NTHR) {
                int ci = i / (TL + 4), p = i - ci * (TL + 4);
                int gl = l0 - 2 + p;
                float v = 0.f;
                if ((unsigned)gl < (unsigned)LLEN)
                    v = xg[xbase + ((size_t)ci * LLEN + gl) * T_STEPS + t];
                xs[ci][p] = v;
            }
        }
        __syncthreads();

        // ---- conv1 -> spikes (fp32, bit-exact). Rows 0..127: 2 full passes ----
#pragma unroll
        for (int p = 0; p < 2; ++p) {
            int sl = p * 64 + lane;                  // 0..127, all lanes active
            float a1[16];
#pragma unroll
            for (int j = 0; j < 16; ++j) a1[j] = b1v[j];
#pragma unroll 4
            for (int ci = 0; ci < CIN; ++ci) {
                float x0 = xs[ci][sl + 0];
                float x1 = xs[ci][sl + 1];
                float x2 = xs[ci][sl + 2];
                const float* w0 = wT1 + (ci * 3 + 0) * C1N + cb;
                const float* w1 = wT1 + (ci * 3 + 1) * C1N + cb;
                const float* w2 = wT1 + (ci * 3 + 2) * C1N + cb;
#pragma unroll
                for (int j = 0; j < 16; ++j) {
                    a1[j] = fmaf(w0[j], x0, a1[j]);
                    a1[j] = fmaf(w1[j], x1, a1[j]);
                    a1[j] = fmaf(w2[j], x2, a1[j]);
                }
            }
            int  gls   = l0 - 1 + sl;
            bool valid = (unsigned)gls < (unsigned)LLEN;
            // pack 16 spikes (bf16 one = 0x3F80) into 8 dwords -> 2 ds_write_b128
            unsigned pk[8];
#pragma unroll
            for (int j = 0; j < 8; ++j) {
                unsigned s0 = (valid && (a1[2*j]   * gain >= th1)) ? 0x3F80u : 0u;
                unsigned s1 = (valid && (a1[2*j+1] * gain >= th1)) ? 0x3F80u : 0u;
                pk[j] = s0 | (s1 << 16);
            }
            unsigned* dstw = (unsigned*)&s1t[sl][cb];
#pragma unroll
            for (int j = 0; j < 8; ++j) dstw[j] = pk[j];
        }
        // ---- halo rows 128,129: 32 lanes, 1 ch x 1 row each (cheap pass) ----
        if (lane < 32) {
            int row = 128 + (lane & 1);
            int ch  = cb + (lane >> 1);
            int gls = l0 - 1 + row;
            bool valid = (unsigned)gls < (unsigned)LLEN;
            float a = b1g[ch];
#pragma unroll
            for (int ci = 0; ci < CIN; ++ci)
#pragma unroll
                for (int k = 0; k < 3; ++k)
                    a = fmaf(wT1[(ci * 3 + k) * C1N + ch], xs[ci][row + k], a);
            s1t[row][ch] = (valid && (a * gain >= th1)) ? 0x3F80u : 0u;
        }
        __syncthreads();

        // ---- conv2 on MFMA pipe + LIF ----
        // D[l][c2] = sum_dk sum_ci s1[l+dk-1][ci] * w2[c2][ci][dk]
        // A[m=l][k=ci]: lane reads 8 contiguous ci at spike row l+dk (16B ds_read)
        const int m  = lane & 15;
        const int q8 = ((lane >> 4) & 3) * 8;
#pragma unroll
        for (int lt = 0; lt < 8; ++lt) {
            f32x4 d = {0.f, 0.f, 0.f, 0.f};
#pragma unroll
            for (int dk = 0; dk < 3; ++dk) {
                int row = lt * 16 + m + dk;
#pragma unroll
                for (int cc = 0; cc < 2; ++cc) {
                    bf16x8 a = *(const bf16x8*)&s1t[row][cc * 32 + q8];
                    d = __builtin_amdgcn_mfma_f32_16x16x32_bf16(a, bw[0][dk][cc], d, 0, 0, 0);
                    d = __builtin_amdgcn_mfma_f32_16x16x32_bf16(a, bw[1][dk][cc], d, 0, 0, 0);
                }
            }
#pragma unroll
            for (int r = 0; r < 4; ++r) {
                float i2 = (d[r] + b2v) * gain;
                float v  = v2s[lt][r] + (i2 - v2s[lt][r]) * (1.0f / 0.9f);
                bool  sp = v >= th2;
                v2s[lt][r]   = sp ? 0.f : v;
                accs[lt][r] += sp ? 1.f : 0.f;
            }
        }
        __syncthreads();
    }

    // ---- reduce acc over l; lanes L, L+16, L+32, L+48 share c2 ----
    float s = 0.f;
#pragma unroll
    for (int lt = 0; lt < 8; ++lt)
#pragma unroll
        for (int r = 0; r < 4; ++r) s += accs[lt][r];
    s += __shfl_down(s, 32, 64);
    s += __shfl_down(s, 16, 64);
    if (lane < 16) atomicAdd(&pooled[b * C2N + cb + lane], s);
}

__global__ __launch_bounds__(NTHR) void fc_kernel(
    const float* __restrict__ pooled, const float* __restrict__ fcw,
    const float* __restrict__ fcb, float* __restrict__ out)
{
    int i = threadIdx.x, b = i >> 2, cls = i & 3;
    float s = 0.f;
#pragma unroll 8
    for (int c = 0; c < C2N; ++c)
        s += pooled[b * C2N + c] * fcw[cls * C2N + c];
    out[b * 4 + cls] = s * (1.0f / ((float)T_STEPS * (float)LLEN)) + fcb[cls];
}

extern "C" void kernel_launch(void* const* d_in, const int* in_sizes, int n_in,
                              void* d_out, int out_size, void* d_ws, size_t ws_size,
                              hipStream_t stream)
{
    const float* xg  = (const float*)d_in[0];
    const float* w1  = (const float*)d_in[1];
    const float* b1  = (const float*)d_in[2];
    const float* w2  = (const float*)d_in[3];
    const float* b2  = (const float*)d_in[4];
    const float* gp  = (const float*)d_in[5];
    const float* t1  = (const float*)d_in[6];
    const float* t2  = (const float*)d_in[7];
    const float* fcw = (const float*)d_in[8];
    const float* fcb = (const float*)d_in[9];
    float* ws  = (float*)d_ws;
    float* out = (float*)d_out;

    const int use_xt = (ws_size >= WS_NEED_B) ? 1 : 0;   // constant per process
    float* xt = (float*)((char*)d_ws + XT_OFF_B);

    hipMemsetAsync(ws + POOL_OFF_F, 0, NB * C2N * sizeof(float), stream);
    prep_weights<<<(C2N * C1N * 3 + NTHR - 1) / NTHR, NTHR, 0, stream>>>(w1, w2, ws);
    if (use_xt)
        transpose_x<<<dim3(LLEN / TXL, NB * CIN), NTHR, 0, stream>>>(xg, xt);
    snn_main<<<dim3(LLEN / TL, NB), NTHR, 0, stream>>>(xg, xt, use_xt,
                                                       b1, b2, gp, t1, t2,
                                                       ws, ws + POOL_OFF_F);
    fc_kernel<<<1, NTHR, 0, stream>>>(ws + POOL_OFF_F, fcw, fcb, out);
}

// Round 3
// 1320.906 us; speedup vs baseline: 1.6469x; 1.4218x over previous
//
#include <hip/hip_runtime.h>

#define T_STEPS 20
#define NB      64
#define CIN     12
#define LLEN    4096
#define C1N     64
#define C2N     64
#define TL      128
#define NTHR    512          // 8 waves: wc = wave&3 (c-tile), wl = wave>>2 (l-half)
#define NT2     256
#define XROWS   (TL + 4)     // 132 x rows, block l in [-2, TL+2)
#define NELEM   (CIN * XROWS)
#define NLD     4            // ceil(1584/512) staged loads per thread
#define S1ROWS  (TL + 2)     // 130 spike rows, block l in [-1, TL+1)
#define S1PITCH 72
#define TXL     256

// ---- ws layout ----
#define W1T_OFF_F   0                     // float [36][64]
#define POOL_OFF_F  2304                  // float [64][64]
#define W2BF_OFF_B  25600                 // ushort [2 hilo][3 dk][c2][ci]
#define XT_OFF_B    (1u << 20)            // float [b][ci][t][l]
#define XT_BYTES    ((size_t)NB * CIN * T_STEPS * LLEN * 4)
#define WS_NEED_B   ((size_t)XT_OFF_B + XT_BYTES)

using bf16x8 = __attribute__((ext_vector_type(8))) short;
using f32x4  = __attribute__((ext_vector_type(4))) float;

__device__ inline unsigned short f32_to_bf16_rne(float f) {
    unsigned u = __builtin_bit_cast(unsigned, f);
    return (unsigned short)((u + 0x7FFFu + ((u >> 16) & 1u)) >> 16);
}

__global__ __launch_bounds__(NT2) void prep_weights(
    const float* __restrict__ w1, const float* __restrict__ w2,
    float* __restrict__ ws)
{
    int i = blockIdx.x * NT2 + threadIdx.x;
    float* w1t = ws + W1T_OFF_F;
    unsigned short* w2b = (unsigned short*)((char*)ws + W2BF_OFF_B);
    if (i < C1N * CIN * 3) {
        int c1 = i / (CIN * 3), r = i % (CIN * 3);
        w1t[r * C1N + c1] = w1[i];
    }
    if (i < C2N * C1N * 3) {
        int dk = i % 3, rem = i / 3;
        int ci = rem % C1N, c2 = rem / C1N;
        float w = w2[i];
        unsigned short hi = f32_to_bf16_rne(w);
        float hif = __builtin_bit_cast(float, (unsigned)hi << 16);
        unsigned short lo = f32_to_bf16_rne(w - hif);
        w2b[((0 * 3 + dk) * C2N + c2) * C1N + ci] = hi;
        w2b[((1 * 3 + dk) * C2N + c2) * C1N + ci] = lo;
    }
}

__global__ __launch_bounds__(NT2) void transpose_x(
    const float* __restrict__ xg, float* __restrict__ xt)
{
    __shared__ float tile[TXL * 21];
    const int tid = threadIdx.x;
    const int l0  = blockIdx.x * TXL;
    const int bci = blockIdx.y;
    const float* src = xg + ((size_t)bci * LLEN + l0) * T_STEPS;
#pragma unroll
    for (int k = 0; k < TXL * T_STEPS / NT2; ++k) {
        int e = tid + k * NT2;
        tile[(e / T_STEPS) * 21 + (e % T_STEPS)] = src[e];
    }
    __syncthreads();
    float* dst = xt + (size_t)bci * T_STEPS * LLEN + l0;
#pragma unroll
    for (int t = 0; t < T_STEPS; ++t)
        dst[(size_t)t * LLEN + tid] = tile[tid * 21 + t];
}

// ---------------------------------------------------------------------------
// Main kernel, pipelined. 8 waves/block: wave (wc,wl) owns channels
// [16wc,16wc+16) x l-half wl. x(t+1) is prefetched into registers during
// compute of t; xs is ping-ponged; 2 barriers per t-step.
// ---------------------------------------------------------------------------
__global__ __launch_bounds__(NTHR, 4) void snn_main(
    const float* __restrict__ xg, const float* __restrict__ xt, int use_xt,
    const float* __restrict__ b1g, const float* __restrict__ b2g,
    const float* __restrict__ gp, const float* __restrict__ t1p,
    const float* __restrict__ t2p,
    const float* __restrict__ ws, float* __restrict__ pooled)
{
    __shared__ __align__(16) float          xs[2][CIN][XROWS];
    __shared__ __align__(16) unsigned short s1t[S1ROWS][S1PITCH];

    const int tid  = threadIdx.x;
    const int lane = tid & 63;
    const int wv   = __builtin_amdgcn_readfirstlane(tid >> 6);
    const int wc   = wv & 3, wl = wv >> 2;
    const int cb   = wc * 16;
    const int b    = blockIdx.y;
    const int l0   = blockIdx.x * TL;

    const float gain = gp[0], th1 = t1p[0], th2 = t2p[0];
    const float* __restrict__ wT1 = ws + W1T_OFF_F;
    const unsigned short* __restrict__ w2b =
        (const unsigned short*)((const char*)ws + W2BF_OFF_B);

    // conv2 B fragments (hi/lo) in registers
    bf16x8 bw[2][3][2];
    {
        int c2  = cb + (lane & 15);
        int ci0 = ((lane >> 4) & 3) * 8;
#pragma unroll
        for (int h = 0; h < 2; ++h)
#pragma unroll
            for (int dk = 0; dk < 3; ++dk)
#pragma unroll
                for (int cc = 0; cc < 2; ++cc)
                    bw[h][dk][cc] = *(const bf16x8*)
                        (w2b + (((h * 3 + dk) * C2N + c2) * C1N + cc * 32 + ci0));
    }
    const float b2v = b2g[cb + (lane & 15)];

    float b1v[16];
#pragma unroll
    for (int j = 0; j < 16; ++j) b1v[j] = b1g[cb + j];

    // LIF state: 64 l x 16 c2 per wave -> [4 lt][4 r]
    float v2s[4][4], accs[4][4];
#pragma unroll
    for (int lt = 0; lt < 4; ++lt)
#pragma unroll
        for (int r = 0; r < 4; ++r) { v2s[lt][r] = 0.f; accs[lt][r] = 0.f; }

    // ---- staging: precompute per-thread offsets, prefetch into pf[] ----
    const size_t xbase = (size_t)b * CIN * LLEN * T_STEPS;
    const float* __restrict__ srcp =
        use_xt ? (xt + (size_t)b * CIN * T_STEPS * LLEN) : (xg + xbase);
    const size_t tstep = use_xt ? (size_t)LLEN : (size_t)1;

    size_t off[NLD];
    bool   ldok[NLD], gok[NLD];
    float  pf[NLD];
#pragma unroll
    for (int k = 0; k < NLD; ++k) {
        int i  = tid + k * NTHR;
        bool w = i < NELEM;
        int iv = w ? i : 0;
        int ci = iv / XROWS, p = iv - ci * XROWS;
        int gl = l0 - 2 + p;
        bool g = w && ((unsigned)gl < (unsigned)LLEN);
        int glc = g ? gl : 0;
        off[k]  = use_xt ? ((size_t)ci * T_STEPS * LLEN + glc)
                         : ((size_t)ci * LLEN + glc) * T_STEPS;
        ldok[k] = w; gok[k] = g;
    }
    float* __restrict__ xsf0 = &xs[0][0][0];
    float* __restrict__ xsf1 = &xs[1][0][0];

    // preamble: pf <- x(0); xs[0] <- pf; pf <- x(1)
#pragma unroll
    for (int k = 0; k < NLD; ++k)
        pf[k] = gok[k] ? srcp[off[k]] : 0.f;
#pragma unroll
    for (int k = 0; k < NLD; ++k)
        if (ldok[k]) xsf0[tid + k * NTHR] = pf[k];
#pragma unroll
    for (int k = 0; k < NLD; ++k)
        pf[k] = gok[k] ? srcp[off[k] + tstep] : 0.f;
    __syncthreads();

    const int m16 = lane & 15;
    const int q8  = ((lane >> 4) & 3) * 8;

#pragma unroll 1
    for (int t = 0; t < T_STEPS; ++t) {
        const float* __restrict__ xc = &xs[t & 1][0][0];

        // ---- conv1 (fp32 VALU, bit-exact): rows wl*64 .. wl*64+63 ----
        {
            int sl = wl * 64 + lane;
            float a1[16];
#pragma unroll
            for (int j = 0; j < 16; ++j) a1[j] = b1v[j];
#pragma unroll 4
            for (int ci = 0; ci < CIN; ++ci) {
                const float* xr = xc + ci * XROWS + sl;
                float x0 = xr[0], x1 = xr[1], x2 = xr[2];
                const float* w0 = wT1 + (ci * 3 + 0) * C1N + cb;
                const float* w1 = wT1 + (ci * 3 + 1) * C1N + cb;
                const float* w2 = wT1 + (ci * 3 + 2) * C1N + cb;
#pragma unroll
                for (int j = 0; j < 16; ++j) {
                    a1[j] = fmaf(w0[j], x0, a1[j]);
                    a1[j] = fmaf(w1[j], x1, a1[j]);
                    a1[j] = fmaf(w2[j], x2, a1[j]);
                }
            }
            int  gls   = l0 - 1 + sl;
            bool valid = (unsigned)gls < (unsigned)LLEN;
            unsigned* dstw = (unsigned*)&s1t[sl][cb];
#pragma unroll
            for (int j = 0; j < 8; ++j) {
                unsigned s0 = (valid && (a1[2*j]   * gain >= th1)) ? 0x3F80u : 0u;
                unsigned s1 = (valid && (a1[2*j+1] * gain >= th1)) ? 0x3F80u : 0u;
                dstw[j] = s0 | (s1 << 16);
            }
        }
        // ---- halo rows 128,129 (wl==0 waves, scalar per (row,ch)) ----
        if (wl == 0 && lane < 32) {
            int row = TL + (lane & 1);
            int ch  = cb + (lane >> 1);
            int gls = l0 - 1 + row;
            bool valid = (unsigned)gls < (unsigned)LLEN;
            float a = b1g[ch];
#pragma unroll
            for (int ci = 0; ci < CIN; ++ci)
#pragma unroll
                for (int k = 0; k < 3; ++k)
                    a = fmaf(wT1[(ci * 3 + k) * C1N + ch], xc[ci * XROWS + row + k], a);
            s1t[row][ch] = (valid && (a * gain >= th1)) ? 0x3F80u : 0u;
        }
        __syncthreads();

        // ---- conv2 (MFMA) + LIF; wave's l-range: wl*64 .. wl*64+63 ----
#pragma unroll
        for (int lt = 0; lt < 4; ++lt) {
            f32x4 d = {0.f, 0.f, 0.f, 0.f};
#pragma unroll
            for (int dk = 0; dk < 3; ++dk) {
                int row = wl * 64 + lt * 16 + m16 + dk;
#pragma unroll
                for (int cc = 0; cc < 2; ++cc) {
                    bf16x8 a = *(const bf16x8*)&s1t[row][cc * 32 + q8];
                    d = __builtin_amdgcn_mfma_f32_16x16x32_bf16(a, bw[0][dk][cc], d, 0, 0, 0);
                    d = __builtin_amdgcn_mfma_f32_16x16x32_bf16(a, bw[1][dk][cc], d, 0, 0, 0);
                }
            }
#pragma unroll
            for (int r = 0; r < 4; ++r) {
                float i2 = (d[r] + b2v) * gain;
                float v  = v2s[lt][r] + (i2 - v2s[lt][r]) * (1.0f / 0.9f);
                bool  sp = v >= th2;
                v2s[lt][r]   = sp ? 0.f : v;
                accs[lt][r] += sp ? 1.f : 0.f;
            }
        }

        // ---- write staged x(t+1), issue loads for x(t+2) ----
        if (t < T_STEPS - 1) {
            float* __restrict__ xn = (t & 1) ? xsf0 : xsf1;
#pragma unroll
            for (int k = 0; k < NLD; ++k)
                if (ldok[k]) xn[tid + k * NTHR] = pf[k];
            if (t < T_STEPS - 2) {
#pragma unroll
                for (int k = 0; k < NLD; ++k)
                    pf[k] = gok[k] ? srcp[off[k] + (size_t)(t + 2) * tstep] : 0.f;
            }
        }
        __syncthreads();
    }

    // ---- reduce acc; lanes L, L+16, L+32, L+48 share c2 ----
    float s = 0.f;
#pragma unroll
    for (int lt = 0; lt < 4; ++lt)
#pragma unroll
        for (int r = 0; r < 4; ++r) s += accs[lt][r];
    s += __shfl_down(s, 32, 64);
    s += __shfl_down(s, 16, 64);
    if (lane < 16) atomicAdd(&pooled[b * C2N + cb + lane], s);
}

__global__ __launch_bounds__(NT2) void fc_kernel(
    const float* __restrict__ pooled, const float* __restrict__ fcw,
    const float* __restrict__ fcb, float* __restrict__ out)
{
    int i = threadIdx.x, b = i >> 2, cls = i & 3;
    float s = 0.f;
#pragma unroll 8
    for (int c = 0; c < C2N; ++c)
        s += pooled[b * C2N + c] * fcw[cls * C2N + c];
    out[b * 4 + cls] = s * (1.0f / ((float)T_STEPS * (float)LLEN)) + fcb[cls];
}

extern "C" void kernel_launch(void* const* d_in, const int* in_sizes, int n_in,
                              void* d_out, int out_size, void* d_ws, size_t ws_size,
                              hipStream_t stream)
{
    const float* xg  = (const float*)d_in[0];
    const float* w1  = (const float*)d_in[1];
    const float* b1  = (const float*)d_in[2];
    const float* w2  = (const float*)d_in[3];
    const float* b2  = (const float*)d_in[4];
    const float* gp  = (const float*)d_in[5];
    const float* t1  = (const float*)d_in[6];
    const float* t2  = (const float*)d_in[7];
    const float* fcw = (const float*)d_in[8];
    const float* fcb = (const float*)d_in[9];
    float* ws  = (float*)d_ws;
    float* out = (float*)d_out;

    const int use_xt = (ws_size >= WS_NEED_B) ? 1 : 0;
    float* xt = (float*)((char*)d_ws + XT_OFF_B);

    hipMemsetAsync(ws + POOL_OFF_F, 0, NB * C2N * sizeof(float), stream);
    prep_weights<<<(C2N * C1N * 3 + NT2 - 1) / NT2, NT2, 0, stream>>>(w1, w2, ws);
    if (use_xt)
        transpose_x<<<dim3(LLEN / TXL, NB * CIN), NT2, 0, stream>>>(xg, xt);
    snn_main<<<dim3(LLEN / TL, NB), NTHR, 0, stream>>>(xg, xt, use_xt,
                                                       b1, b2, gp, t1, t2,
                                                       ws, ws + POOL_OFF_F);
    fc_kernel<<<1, NT2, 0, stream>>>(ws + POOL_OFF_F, fcw, fcb, out);
}